// Round 1
// baseline (138.663 us; speedup 1.0000x reference)
//
#include <hip/hip_runtime.h>
#include <stdint.h>
#include <stddef.h>

typedef int v4i __attribute__((ext_vector_type(4)));

#define GLOAD_LDS16(g, l) __builtin_amdgcn_global_load_lds( \
    (const __attribute__((address_space(1))) void*)(g),     \
    (__attribute__((address_space(3))) void*)(l), 16, 0, 0)

// ---------------------------------------------------------------------------
// Quantize rows of length 2048: one wave per row, 4 rows per 256-thread block.
// scale = max(amax/127, floorv); q = clip(rint(v/scale), -128, 127)
// (IEEE div + rintf == numpy round-half-even semantics)
// ---------------------------------------------------------------------------
__device__ __forceinline__ int pack4(float4 f, float s) {
    int a = (int)rintf(f.x / s); a = a < -128 ? -128 : (a > 127 ? 127 : a);
    int b = (int)rintf(f.y / s); b = b < -128 ? -128 : (b > 127 ? 127 : b);
    int c = (int)rintf(f.z / s); c = c < -128 ? -128 : (c > 127 ? 127 : c);
    int d = (int)rintf(f.w / s); d = d < -128 ? -128 : (d > 127 ? 127 : d);
    return (a & 255) | ((b & 255) << 8) | ((c & 255) << 16) | ((d & 255) << 24);
}

__global__ __launch_bounds__(256) void quant_rows_2048(
    const float* __restrict__ in, signed char* __restrict__ q,
    float* __restrict__ scales, float floorv)
{
    const int lane = threadIdx.x & 63;
    const int row  = blockIdx.x * 4 + (threadIdx.x >> 6);
    const float* rp = in + (size_t)row * 2048;

    float4 v[8];
#pragma unroll
    for (int j = 0; j < 2; ++j) {
        const float4* p = (const float4*)(rp + j * 1024 + lane * 16);
#pragma unroll
        for (int i = 0; i < 4; ++i) v[j * 4 + i] = p[i];
    }
    float am = 0.0f;
#pragma unroll
    for (int i = 0; i < 8; ++i) {
        am = fmaxf(am, fabsf(v[i].x));
        am = fmaxf(am, fabsf(v[i].y));
        am = fmaxf(am, fabsf(v[i].z));
        am = fmaxf(am, fabsf(v[i].w));
    }
#pragma unroll
    for (int off = 32; off; off >>= 1) am = fmaxf(am, __shfl_xor(am, off));
    const float s = fmaxf(am / 127.0f, floorv);

#pragma unroll
    for (int j = 0; j < 2; ++j) {
        int4 pk;
        pk.x = pack4(v[j * 4 + 0], s);
        pk.y = pack4(v[j * 4 + 1], s);
        pk.z = pack4(v[j * 4 + 2], s);
        pk.w = pack4(v[j * 4 + 3], s);
        *(int4*)(q + (size_t)row * 2048 + j * 1024 + lane * 16) = pk;
    }
    if (lane == 0) scales[row] = s;
}

// ---------------------------------------------------------------------------
// int8 GEMM: out[M=16384, O=2048] = xq[M,K=2048] . wq[O,K]^T, int32 accum,
// dequant y = acc * xs[row] * ws[col] + bias[col].
// 128x128 tile, BK=128, 4 waves (2x2), per-wave 64x64 via 4x4 mfma 16x16x64.
// LDS: linear dest for global_load_lds; XOR chunk-swizzle (chunk ^ (row&7))
// applied to the *global source* on stage and to the ds_read address (rule 21).
// ---------------------------------------------------------------------------
__global__ __launch_bounds__(256) void gemm_i8(
    const signed char* __restrict__ xq, const signed char* __restrict__ wq,
    const float* __restrict__ xs, const float* __restrict__ ws,
    const float* __restrict__ bias, float* __restrict__ out, int K)
{
    __shared__ __align__(16) signed char ldsA[128 * 128];
    __shared__ __align__(16) signed char ldsB[128 * 128];

    const int tid  = threadIdx.x;
    const int lane = tid & 63;
    const int wid  = tid >> 6;
    const int wm   = wid >> 1;       // 0..1
    const int wn   = wid & 1;        // 0..1
    const int brow = blockIdx.y * 128;
    const int bcol = blockIdx.x * 128;

    v4i acc[4][4] = {};

    const int r_sub  = tid >> 3;     // 0..31 (row within 32-row staging chunk)
    const int chunk  = tid & 7;      // 16B chunk slot within 128B row
    const int nkt    = K >> 7;

    for (int kt = 0; kt < nkt; ++kt) {
        const size_t kbase = (size_t)kt * 128;
#pragma unroll
        for (int c = 0; c < 4; ++c) {
            const int r = c * 32 + r_sub;
            const int g = chunk ^ (r & 7);   // inverse-swizzled global chunk
            GLOAD_LDS16(xq + (size_t)(brow + r) * K + kbase + g * 16,
                        &ldsA[r * 128 + chunk * 16]);
        }
#pragma unroll
        for (int c = 0; c < 4; ++c) {
            const int r = c * 32 + r_sub;
            const int g = chunk ^ (r & 7);
            GLOAD_LDS16(wq + (size_t)(bcol + r) * K + kbase + g * 16,
                        &ldsB[r * 128 + chunk * 16]);
        }
        __syncthreads();

        const int ko = lane >> 4;    // 0..3 (k group)
        const int rl = lane & 15;
#pragma unroll
        for (int kk = 0; kk < 2; ++kk) {
            v4i af[4], bf[4];
#pragma unroll
            for (int m = 0; m < 4; ++m) {
                const int row = wm * 64 + m * 16 + rl;
                const int sc  = (kk * 4 + ko) ^ (row & 7);
                af[m] = *(const v4i*)&ldsA[row * 128 + sc * 16];
            }
#pragma unroll
            for (int n = 0; n < 4; ++n) {
                const int row = wn * 64 + n * 16 + rl;
                const int sc  = (kk * 4 + ko) ^ (row & 7);
                bf[n] = *(const v4i*)&ldsB[row * 128 + sc * 16];
            }
#pragma unroll
            for (int m = 0; m < 4; ++m)
#pragma unroll
                for (int n = 0; n < 4; ++n)
                    acc[m][n] = __builtin_amdgcn_mfma_i32_16x16x64_i8(
                        af[m], bf[n], acc[m][n], 0, 0, 0);
        }
        __syncthreads();
    }

    // Epilogue: C/D layout col = lane&15, row = (lane>>4)*4 + j
    const int rl = lane & 15;
    const int rg = lane >> 4;
#pragma unroll
    for (int n = 0; n < 4; ++n) {
        const int col = bcol + wn * 64 + n * 16 + rl;
        const float wsc = ws[col];
        const float bv  = bias[col];
#pragma unroll
        for (int m = 0; m < 4; ++m) {
#pragma unroll
            for (int j = 0; j < 4; ++j) {
                const int row = brow + wm * 64 + m * 16 + rg * 4 + j;
                out[(size_t)row * 2048 + col] =
                    (float)acc[m][n][j] * xs[row] * wsc + bv;
            }
        }
    }
}

// ---------------------------------------------------------------------------
extern "C" void kernel_launch(void* const* d_in, const int* in_sizes, int n_in,
                              void* d_out, int out_size, void* d_ws, size_t ws_size,
                              hipStream_t stream) {
    const float* x    = (const float*)d_in[0];   // [B,N,D] = [4,4096,2048]
    const float* w    = (const float*)d_in[1];   // [O,D]   = [2048,2048]
    const float* bias = (const float*)d_in[2];   // [O]
    float* out = (float*)d_out;

    const int D = 2048;
    const int O = in_sizes[2];                   // 2048
    const int M = in_sizes[0] / D;               // 16384

    char* wsb = (char*)d_ws;
    signed char* xq = (signed char*)wsb;                         // M*D   = 33554432 B
    signed char* wqp = (signed char*)(wsb + (size_t)M * D);      // O*D   =  4194304 B
    float* xs  = (float*)(wsb + (size_t)M * D + (size_t)O * D);  // M*4   =    65536 B
    float* wsc = (float*)(wsb + (size_t)M * D + (size_t)O * D + (size_t)M * 4); // O*4

    // quantize x: M rows, 4 rows/block
    quant_rows_2048<<<M / 4, 256, 0, stream>>>(x, xq, xs, 1e-12f);
    // quantize w: O rows; floor = clip(max,1e-8)/127 == max(max/127, 1e-8/127)
    quant_rows_2048<<<O / 4, 256, 0, stream>>>(w, wqp, wsc, 1e-8f / 127.0f);

    dim3 grid(O / 128, M / 128);
    gemm_i8<<<grid, 256, 0, stream>>>(xq, wqp, xs, wsc, bias, out, D);
}

// Round 2
// 125.968 us; speedup vs baseline: 1.1008x; 1.1008x over previous
//
#include <hip/hip_runtime.h>
#include <stdint.h>
#include <stddef.h>

typedef int v4i __attribute__((ext_vector_type(4)));

#define GLOAD_LDS16(g, l) __builtin_amdgcn_global_load_lds( \
    (const __attribute__((address_space(1))) void*)(g),     \
    (__attribute__((address_space(3))) void*)(l), 16, 0, 0)

// ---------------------------------------------------------------------------
// Quantize rows of length 2048: one wave per row, 4 rows per 256-thread block.
// scale = max(amax/127, floorv); q = clip(rint(v/scale), -128, 127)
// ---------------------------------------------------------------------------
__device__ __forceinline__ int pack4(float4 f, float s) {
    int a = (int)rintf(f.x / s); a = a < -128 ? -128 : (a > 127 ? 127 : a);
    int b = (int)rintf(f.y / s); b = b < -128 ? -128 : (b > 127 ? 127 : b);
    int c = (int)rintf(f.z / s); c = c < -128 ? -128 : (c > 127 ? 127 : c);
    int d = (int)rintf(f.w / s); d = d < -128 ? -128 : (d > 127 ? 127 : d);
    return (a & 255) | ((b & 255) << 8) | ((c & 255) << 16) | ((d & 255) << 24);
}

__global__ __launch_bounds__(256) void quant_rows_2048(
    const float* __restrict__ in, signed char* __restrict__ q,
    float* __restrict__ scales, float floorv)
{
    const int lane = threadIdx.x & 63;
    const int row  = blockIdx.x * 4 + (threadIdx.x >> 6);
    const float* rp = in + (size_t)row * 2048;

    float4 v[8];
#pragma unroll
    for (int j = 0; j < 2; ++j) {
        const float4* p = (const float4*)(rp + j * 1024 + lane * 16);
#pragma unroll
        for (int i = 0; i < 4; ++i) v[j * 4 + i] = p[i];
    }
    float am = 0.0f;
#pragma unroll
    for (int i = 0; i < 8; ++i) {
        am = fmaxf(am, fabsf(v[i].x));
        am = fmaxf(am, fabsf(v[i].y));
        am = fmaxf(am, fabsf(v[i].z));
        am = fmaxf(am, fabsf(v[i].w));
    }
#pragma unroll
    for (int off = 32; off; off >>= 1) am = fmaxf(am, __shfl_xor(am, off));
    const float s = fmaxf(am / 127.0f, floorv);

#pragma unroll
    for (int j = 0; j < 2; ++j) {
        int4 pk;
        pk.x = pack4(v[j * 4 + 0], s);
        pk.y = pack4(v[j * 4 + 1], s);
        pk.z = pack4(v[j * 4 + 2], s);
        pk.w = pack4(v[j * 4 + 3], s);
        *(int4*)(q + (size_t)row * 2048 + j * 1024 + lane * 16) = pk;
    }
    if (lane == 0) scales[row] = s;
}

// ---------------------------------------------------------------------------
// Pipelined int8 GEMM: out[M,2048] = xq[M,K] . wq[O,K]^T  (int32 accum),
// dequant y = acc * xs[row] * ws[col] + bias[col].
//
// 256x256 tile, BK=64 (64B rows), 512 threads = 8 waves (2M x 4N),
// per-wave 128x64 via 8x4 fragments of mfma_i32_16x16x64_i8.
// 4-deep LDS ring (4 x (16KB A + 16KB B) = 128KB), prefetch depth 3 K-tiles.
// 4 phases per K-tile: {ds_read subtile | 1 gload for t+3 | s_barrier |
//   lgkmcnt(0) | setprio(1) 8xMFMA setprio(0) | s_barrier}.
// Counted vmcnt(8) before tile-end barrier (never 0 in main loop).
// LDS swizzle: lds slot s of row r holds global chunk s ^ ((r>>1)&3)
// (2-way bank aliasing = free); applied on gload SOURCE and ds_read addr.
// ---------------------------------------------------------------------------
__global__ __launch_bounds__(512, 2) void gemm_i8_pipe(
    const signed char* __restrict__ xq, const signed char* __restrict__ wq,
    const float* __restrict__ xs, const float* __restrict__ ws,
    const float* __restrict__ bias, float* __restrict__ out, int K)
{
    __shared__ __align__(16) signed char lds[131072]; // [A:4x16KB][B:4x16KB]

    const int tid  = threadIdx.x;
    const int lane = tid & 63;
    const int wid  = tid >> 6;        // 0..7
    const int wm   = wid >> 2;        // 0..1
    const int wn   = wid & 3;         // 0..3

    // XCD-bijective block swizzle (nwg = 512, divisible by 8)
    const int nwg  = gridDim.x * gridDim.y;
    int orig = blockIdx.y * gridDim.x + blockIdx.x;
    int swz  = ((nwg & 7) == 0) ? ((orig & 7) * (nwg >> 3) + (orig >> 3)) : orig;
    const int brow = (swz / gridDim.x) * 256;
    const int bcol = (swz % gridDim.x) * 256;

    // staging coords: thread covers (row = tid>>2, chunk = tid&3) of a half
    const int srow = tid >> 2;                                   // 0..127
    const int gch  = (((tid & 3) ^ ((tid >> 3) & 3)) << 4);      // swizzled src byte
    const int lofs = tid << 4;                                   // linear LDS dest
    const signed char* gA = xq + (size_t)(brow + srow) * K;
    const signed char* gB = wq + (size_t)(bcol + srow) * K;

#define ST_A(tt, half) GLOAD_LDS16(gA + (size_t)(half) * 128 * K + (size_t)(tt) * 64 + gch, \
                                   lds + ((((tt) & 3) << 14) + ((half) << 13) + lofs))
#define ST_B(tt, half) GLOAD_LDS16(gB + (size_t)(half) * 128 * K + (size_t)(tt) * 64 + gch, \
                                   lds + (65536 + (((tt) & 3) << 14) + ((half) << 13) + lofs))

    // fragment read coords
    const int rl   = lane & 15;
    const int ko   = lane >> 4;                       // k-chunk 0..3
    const int slot = ((ko ^ ((rl >> 1) & 3)) << 4);   // swizzled ds_read byte

#define FRAG_A(buf, r) (*(const v4i*)(lds + (((buf) << 14) + (r) * 64 + slot)))
#define FRAG_B(buf, r) (*(const v4i*)(lds + (65536 + ((buf) << 14) + (r) * 64 + slot)))

    v4i acc[8][4] = {};

#define MFMA8(M0, M1)                                                              \
    do {                                                                           \
        __builtin_amdgcn_s_setprio(1);                                             \
        acc[M0][0] = __builtin_amdgcn_mfma_i32_16x16x64_i8(a0, bf0, acc[M0][0], 0, 0, 0); \
        acc[M0][1] = __builtin_amdgcn_mfma_i32_16x16x64_i8(a0, bf1, acc[M0][1], 0, 0, 0); \
        acc[M0][2] = __builtin_amdgcn_mfma_i32_16x16x64_i8(a0, bf2, acc[M0][2], 0, 0, 0); \
        acc[M0][3] = __builtin_amdgcn_mfma_i32_16x16x64_i8(a0, bf3, acc[M0][3], 0, 0, 0); \
        acc[M1][0] = __builtin_amdgcn_mfma_i32_16x16x64_i8(a1, bf0, acc[M1][0], 0, 0, 0); \
        acc[M1][1] = __builtin_amdgcn_mfma_i32_16x16x64_i8(a1, bf1, acc[M1][1], 0, 0, 0); \
        acc[M1][2] = __builtin_amdgcn_mfma_i32_16x16x64_i8(a1, bf2, acc[M1][2], 0, 0, 0); \
        acc[M1][3] = __builtin_amdgcn_mfma_i32_16x16x64_i8(a1, bf3, acc[M1][3], 0, 0, 0); \
        __builtin_amdgcn_s_setprio(0);                                             \
    } while (0)

#define BAR()  __builtin_amdgcn_s_barrier()
#define LGKM0() asm volatile("s_waitcnt lgkmcnt(0)" ::: "memory")

    auto tile = [&](int t, bool issue) {
        const int buf = t & 3;
        const int ar  = wm * 128 + rl;   // base A row for this lane
        const int br  = wn * 64 + rl;    // base B row for this lane
        // ---- phase 0: all 4 B-frags + A m0,m1; stage A half0 of t+3
        v4i bf0 = FRAG_B(buf, br);
        v4i bf1 = FRAG_B(buf, br + 16);
        v4i bf2 = FRAG_B(buf, br + 32);
        v4i bf3 = FRAG_B(buf, br + 48);
        v4i a0  = FRAG_A(buf, ar);
        v4i a1  = FRAG_A(buf, ar + 16);
        if (issue) ST_A(t + 3, 0);
        BAR(); LGKM0();
        MFMA8(0, 1);
        BAR();
        // ---- phase 1: A m2,m3; stage A half1
        a0 = FRAG_A(buf, ar + 32);
        a1 = FRAG_A(buf, ar + 48);
        if (issue) ST_A(t + 3, 1);
        BAR(); LGKM0();
        MFMA8(2, 3);
        BAR();
        // ---- phase 2: A m4,m5; stage B half0
        a0 = FRAG_A(buf, ar + 64);
        a1 = FRAG_A(buf, ar + 80);
        if (issue) ST_B(t + 3, 0);
        BAR(); LGKM0();
        MFMA8(4, 5);
        BAR();
        // ---- phase 3: A m6,m7; stage B half1 (tile-end vmcnt+barrier by caller)
        a0 = FRAG_A(buf, ar + 96);
        a1 = FRAG_A(buf, ar + 112);
        if (issue) ST_B(t + 3, 1);
        BAR(); LGKM0();
        MFMA8(6, 7);
    };

    // ---- prologue: stage tiles 0,1,2 (FIFO, tile-major); guard tile 0
    ST_A(0, 0); ST_A(0, 1); ST_B(0, 0); ST_B(0, 1);
    ST_A(1, 0); ST_A(1, 1); ST_B(1, 0); ST_B(1, 1);
    ST_A(2, 0); ST_A(2, 1); ST_B(2, 0); ST_B(2, 1);
    asm volatile("s_waitcnt vmcnt(8)" ::: "memory");
    BAR();

    const int NT = K >> 6;   // 32
    int t = 0;
    for (; t < NT - 3; ++t) {
        tile(t, true);
        asm volatile("s_waitcnt vmcnt(8)" ::: "memory");  // guard t+1 (2 tiles stay in flight)
        BAR();
    }
    tile(NT - 3, false);
    asm volatile("s_waitcnt vmcnt(4)" ::: "memory");      // guard NT-2
    BAR();
    tile(NT - 2, false);
    asm volatile("s_waitcnt vmcnt(0)" ::: "memory");      // guard NT-1
    BAR();
    tile(NT - 1, false);

    // ---- epilogue: C/D layout col = lane&15, row = (lane>>4)*4 + j
    const int rg = lane >> 4;
#pragma unroll
    for (int n = 0; n < 4; ++n) {
        const int col = bcol + wn * 64 + n * 16 + rl;
        const float wsc = ws[col];
        const float bv  = bias[col];
#pragma unroll
        for (int m = 0; m < 8; ++m) {
#pragma unroll
            for (int j = 0; j < 4; ++j) {
                const int row = brow + wm * 128 + m * 16 + rg * 4 + j;
                out[(size_t)row * 2048 + col] =
                    (float)acc[m][n][j] * xs[row] * wsc + bv;
            }
        }
    }
#undef ST_A
#undef ST_B
#undef FRAG_A
#undef FRAG_B
#undef MFMA8
#undef BAR
#undef LGKM0
}

// ---------------------------------------------------------------------------
extern "C" void kernel_launch(void* const* d_in, const int* in_sizes, int n_in,
                              void* d_out, int out_size, void* d_ws, size_t ws_size,
                              hipStream_t stream) {
    const float* x    = (const float*)d_in[0];   // [B,N,D] = [4,4096,2048]
    const float* w    = (const float*)d_in[1];   // [O,D]   = [2048,2048]
    const float* bias = (const float*)d_in[2];   // [O]
    float* out = (float*)d_out;

    const int D = 2048;
    const int O = in_sizes[2];                   // 2048
    const int M = in_sizes[0] / D;               // 16384

    char* wsb = (char*)d_ws;
    signed char* xq  = (signed char*)wsb;
    signed char* wqp = (signed char*)(wsb + (size_t)M * D);
    float* xs  = (float*)(wsb + (size_t)M * D + (size_t)O * D);
    float* wsc = (float*)(wsb + (size_t)M * D + (size_t)O * D + (size_t)M * 4);

    quant_rows_2048<<<M / 4, 256, 0, stream>>>(x, xq, xs, 1e-12f);
    quant_rows_2048<<<O / 4, 256, 0, stream>>>(w, wqp, wsc, 1e-8f / 127.0f);

    dim3 grid(O / 256, M / 256);   // (8, 64) = 512 blocks
    gemm_i8_pipe<<<grid, 512, 0, stream>>>(xq, wqp, xs, wsc, bias, out, D);
}